// Round 3
// baseline (298.285 us; speedup 1.0000x reference)
//
#include <hip/hip_runtime.h>

// Problem constants (GNNNet_678604833376): B=2, N=50000, D=128, E=640000
#define NNODES 50000
#define NBATCH 2
#define DIM    128
#define NEDGE  640000
#define M_TOT  (NBATCH*NNODES)   // 100000 rows for the GEMM
#define NXCD   8
#define NBL_N  196               // ceil(NNODES/256)

typedef unsigned short u16;
typedef unsigned int   u32;
typedef unsigned long long u64;

typedef __attribute__((ext_vector_type(8))) short bf16x8;   // 8 bf16 = 4 VGPRs
typedef __attribute__((ext_vector_type(4))) float f32x4;
typedef __attribute__((ext_vector_type(2))) u32   u32x2;
typedef __attribute__((ext_vector_type(4))) u32   u32x4;

__device__ __forceinline__ float bf2f(u16 u){ return __uint_as_float(((u32)u)<<16); }
__device__ __forceinline__ u16 f2bf(float f){
    u32 x = __float_as_uint(f);
    x += 0x7fffu + ((x>>16)&1u);   // round-to-nearest-even
    return (u16)(x>>16);
}

// ---------- histogram: per-XCD partials, L2-resident workgroup-scope atomics ----------
__global__ __launch_bounds__(256) void count_k(const int* __restrict__ ei,
                                               const float* __restrict__ ea,
                                               u64* __restrict__ part,
                                               u32* __restrict__ rankpack){
    u32 xcc = __builtin_amdgcn_s_getreg(6164) & 7u;   // HW_REG_XCC_ID
    int e = blockIdx.x*256 + threadIdx.x;
    if (e < NEDGE){
        int c = __builtin_nontemporal_load(ei + NEDGE + e);
        float w = __builtin_nontemporal_load(ea + e);
        u64 inc = (((u64)__float2uint_rn(w * 16777216.0f)) << 32) | 1ull;
        u64 old = __hip_atomic_fetch_add(&part[(size_t)xcc*NNODES + c], inc,
                                         __ATOMIC_RELAXED, __HIP_MEMORY_SCOPE_WORKGROUP);
        __builtin_nontemporal_store(((u32)old & 0xffffu) | (xcc << 16), rankpack + e);
    }
}

// ---------- fused reduce + block-scan ----------
__global__ __launch_bounds__(256) void scan1(const u64* __restrict__ part,
                                             int* __restrict__ cnt,
                                             int* __restrict__ poff,
                                             float* __restrict__ dinv,
                                             int* colstart, int* bsum){
    __shared__ int s[256];
    int tid = threadIdx.x;
    int n = blockIdx.x*256 + tid;
    int v = 0;
    if (n < NNODES){
        int run = 0; u64 fsum = 0;
        #pragma unroll
        for (int p = 0; p < NXCD; ++p){
            u64 pv = __builtin_nontemporal_load(part + (size_t)p*NNODES + n);
            poff[p*NNODES + n] = run;
            run  += (int)(pv & 0xffffffffu);
            fsum += (pv >> 32);
        }
        cnt[n] = run;
        v = run;
        float deg = 1.0f + (float)fsum * (1.0f/16777216.0f);   // deg >= 1
        dinv[n] = rsqrtf(deg);
    }
    s[tid] = v; __syncthreads();
    #pragma unroll
    for (int off = 1; off < 256; off <<= 1){
        int t = (tid >= off) ? s[tid-off] : 0;
        __syncthreads();
        s[tid] += t;
        __syncthreads();
    }
    if (n < NNODES) colstart[n] = s[tid] - v;     // exclusive within block
    if (tid == 255) bsum[blockIdx.x] = s[255];
}

// ---------- CSR bucket fill + inline bsum-scan ----------
// epk[pos] = row | (bf16(norm) << 16)   (row < 50000 fits in 16 bits)
__global__ __launch_bounds__(256) void fill_k(const int* __restrict__ ei,
                                              const float* __restrict__ ea,
                                              const float* __restrict__ dinv,
                                              const int* __restrict__ colstart,
                                              const int* __restrict__ bsum,
                                              const int* __restrict__ poff,
                                              const u32* __restrict__ rankpack,
                                              int* __restrict__ colstartF,
                                              u32* __restrict__ epk){
    __shared__ int s[256];
    __shared__ int pre[256];
    int tid = threadIdx.x;
    int v = (tid < NBL_N) ? bsum[tid] : 0;
    s[tid] = v; __syncthreads();
    #pragma unroll
    for (int off = 1; off < 256; off <<= 1){
        int t = (tid >= off) ? s[tid-off] : 0;
        __syncthreads();
        s[tid] += t;
        __syncthreads();
    }
    pre[tid] = s[tid] - v;                        // exclusive prefix of bsum
    __syncthreads();

    int e = blockIdx.x*256 + tid;
    if (e < NEDGE){
        int r = __builtin_nontemporal_load(ei + e);
        int c = __builtin_nontemporal_load(ei + NEDGE + e);
        float av = __builtin_nontemporal_load(ea + e);
        u32 rp = __builtin_nontemporal_load(rankpack + e);
        int base = colstart[c] + pre[c >> 8];     // final colstart for c
        colstartF[c] = base;
        int pos = base + poff[(rp >> 16)*NNODES + c] + (int)(rp & 0xffffu);
        float w = dinv[r] * av * dinv[c];
        epk[pos] = (u32)r | ((u32)f2bf(w) << 16);   // regular store: re-read by both gathers
    }
}

// transpose both W (fp32) -> Wt (bf16), Wt[n][k] = W[k][n]; also zero part[].
__global__ __launch_bounds__(256) void transposeW(const float* __restrict__ W1, u16* __restrict__ Wt1,
                                                  const float* __restrict__ W2, u16* __restrict__ Wt2,
                                                  u64* __restrict__ part){
    int i = blockIdx.x*256 + threadIdx.x;         // 128 x 256 = 32768 threads
    const float* W = (i < 16384) ? W1 : W2;
    u16* Wt       = (i < 16384) ? Wt1 : Wt2;
    int ii = i & 16383;
    int k = ii >> 7, n = ii & 127;
    Wt[n*DIM + k] = f2bf(W[ii]);
    // zero the 8x50000 u64 histogram: 400000 u64 / 32768 thr = 13 each
    for (int z = i; z < NXCD*NNODES; z += 32768) part[z] = 0;
}

// ---------- GEMM: H(bf16) = A(AT->bf16) @ W[128,128] ----------
// PERM: store row arow (= b*N+n) to interleaved row 2n+b; else identity.
// 128-row tiles (grid 782 -> 3.05 blocks/CU balance), LDS-staged vectorized
// epilogue reusing the W buffer. H stores are REGULAR (L2-warm for gather).
__device__ __forceinline__ bf16x8 load_frag(const float* A, size_t off){
    // x input: read exactly once, never reused -> nt keeps L2 clean for H
    const f32x4* ap = (const f32x4*)(A + off);
    f32x4 lo = __builtin_nontemporal_load(ap);
    f32x4 hi = __builtin_nontemporal_load(ap + 1);
    bf16x8 r;
    r[0] = (short)f2bf(lo.x); r[1] = (short)f2bf(lo.y);
    r[2] = (short)f2bf(lo.z); r[3] = (short)f2bf(lo.w);
    r[4] = (short)f2bf(hi.x); r[5] = (short)f2bf(hi.y);
    r[6] = (short)f2bf(hi.z); r[7] = (short)f2bf(hi.w);
    return r;
}
__device__ __forceinline__ bf16x8 load_frag(const u16* A, size_t off){
    // o1 input: just written by gather1 -> want the L2 hit, regular load
    return *(const bf16x8*)(A + off);
}

template <typename AT, bool PERM>
__global__ __launch_bounds__(256) void gemm128(const AT* __restrict__ A,
                                               const u16* __restrict__ Wt,
                                               u16* __restrict__ H, int M){
    __shared__ u16 Wl[128][136];   // +8 pad: 272B row (17x16B) keeps 16B align; reused as C-stage
    int tid = threadIdx.x;
    {
        const uint4* src = (const uint4*)Wt;   // 2048 x 16B
        #pragma unroll
        for (int j = 0; j < 8; ++j){
            int g = tid + j*256;
            int n = g >> 4;
            int k = (g & 15) * 8;
            *(uint4*)&Wl[n][k] = src[g];
        }
    }
    __syncthreads();

    int wave = tid >> 6, lane = tid & 63;
    int quad = lane >> 4, r = lane & 15;
    int row0 = blockIdx.x*128;
    int rbase = row0 + wave*32;

    f32x4 acc[2][8];
    #pragma unroll
    for (int mt = 0; mt < 2; ++mt)
        #pragma unroll
        for (int nt = 0; nt < 8; ++nt)
            acc[mt][nt] = (f32x4){0.f,0.f,0.f,0.f};

    #pragma unroll
    for (int ks = 0; ks < 4; ++ks){
        bf16x8 af[2];
        #pragma unroll
        for (int mt = 0; mt < 2; ++mt){
            int row = rbase + mt*16 + r;
            if (row < M)
                af[mt] = load_frag(A, (size_t)row*DIM + ks*32 + quad*8);
            else
                af[mt] = (bf16x8){0,0,0,0,0,0,0,0};
        }
        #pragma unroll
        for (int nt = 0; nt < 8; ++nt){
            bf16x8 bfr = *(const bf16x8*)&Wl[nt*16 + r][ks*32 + quad*8];
            #pragma unroll
            for (int mt = 0; mt < 2; ++mt)
                acc[mt][nt] = __builtin_amdgcn_mfma_f32_16x16x32_bf16(af[mt], bfr, acc[mt][nt], 0, 0, 0);
        }
    }

    // all waves done reading Wl -> reuse as C-stage
    __syncthreads();
    // C/D layout: col = lane&15 (=r), row = quad*4 + reg
    #pragma unroll
    for (int mt = 0; mt < 2; ++mt)
        #pragma unroll
        for (int nt = 0; nt < 8; ++nt)
            #pragma unroll
            for (int reg = 0; reg < 4; ++reg)
                Wl[wave*32 + mt*16 + quad*4 + reg][nt*16 + r] = f2bf(acc[mt][nt][reg]);
    __syncthreads();

    // vectorized, coalesced 16B REGULAR stores (H is re-read by gather: keep in L2)
    #pragma unroll
    for (int j = 0; j < 8; ++j){
        int g = tid + j*256;                  // 2048 chunks = 128 rows x 16 chunks
        int rl = g >> 4, ch = g & 15;
        int row = row0 + rl;
        if (row < M){
            size_t hrow;
            if (PERM){
                int b = (row >= NNODES);
                hrow = (size_t)(2*(row - b*NNODES) + b);
            } else {
                hrow = (size_t)row;
            }
            u32x4 vv = *(const u32x4*)&Wl[rl][ch*8];
            *(u32x4*)((char*)H + hrow*256 + ch*16) = vv;
        }
    }
}

// ---------- gather-aggregate: one wave = one node, BOTH batches ----------
// H interleaved: Hi[n][batch][128] bf16 -> one edge = one contiguous 512B
// wave-load. 16 loads in flight per wave (latency-bound, VGPRs are cheap:
// round-1 showed 28 VGPRs @ 34% VALUBusy -> deepen the MLP window).
template <bool OUT_F32>
__global__ __launch_bounds__(256) void gather6_k(const u16* __restrict__ Hi,
                                                 const u32* __restrict__ epk,
                                                 const int* __restrict__ colstartF,
                                                 const int* __restrict__ cnt,
                                                 const float* __restrict__ dinv,
                                                 const float* __restrict__ bias,
                                                 void* __restrict__ out){
    int wave = threadIdx.x >> 6, lane = threadIdx.x & 63;
    int n = blockIdx.x*4 + wave;
    if (n >= NNODES) return;
    const char* Hb = (const char*)Hi;             // row stride 512 B (both batches)

    float a0, a1, a2, a3;
    {
        uint2 sv = *(const uint2*)(Hb + (size_t)n*512 + lane*8);
        float dn = dinv[n], dn2 = dn*dn;
        a0 = dn2*__uint_as_float(sv.x << 16);
        a1 = dn2*__uint_as_float(sv.x & 0xffff0000u);
        a2 = dn2*__uint_as_float(sv.y << 16);
        a3 = dn2*__uint_as_float(sv.y & 0xffff0000u);
    }

    int s = colstartF[n], c = cnt[n];
    for (int base = 0; base < c; base += 64){
        int m = min(64, c - base);
        u32 em = 0;                               // pad: row 0, weight +0.0f
        if (lane < m) em = __builtin_nontemporal_load(epk + s + base + lane);
        for (int j = 0; j < m; j += 16){          // 16 edges per iter, 16 loads in flight
            uint2 v[16]; float w[16];
            #pragma unroll
            for (int g = 0; g < 16; ++g){
                u32 me = __shfl(em, j + g);       // max idx 48+15 = 63
                v[g] = *(const uint2*)(Hb + (size_t)(me & 0xffffu)*512 + lane*8);
                w[g] = __uint_as_float(me & 0xffff0000u);
            }
            #pragma unroll
            for (int g = 0; g < 16; ++g){
                a0 = fmaf(w[g], __uint_as_float(v[g].x << 16), a0);
                a1 = fmaf(w[g], __uint_as_float(v[g].x & 0xffff0000u), a1);
                a2 = fmaf(w[g], __uint_as_float(v[g].y << 16), a2);
                a3 = fmaf(w[g], __uint_as_float(v[g].y & 0xffff0000u), a3);
            }
        }
    }

    int sub = lane & 31, b = lane >> 5;
    float4 bb = ((const float4*)bias)[sub];       // cols [4*sub .. 4*sub+4), same both batches
    a0 = fmaxf(a0 + bb.x, 0.f);
    a1 = fmaxf(a1 + bb.y, 0.f);
    a2 = fmaxf(a2 + bb.z, 0.f);
    a3 = fmaxf(a3 + bb.w, 0.f);
    if (OUT_F32){
        // de-interleave: d_out row = b*N + n (fp32). Final output: nt store.
        float* O = (float*)out + ((size_t)b*NNODES + n)*DIM + sub*4;
        f32x4 vo = (f32x4){a0, a1, a2, a3};
        __builtin_nontemporal_store(vo, (f32x4*)O);
    } else {
        // stay interleaved (bf16): row 2n+b == byte offset n*512 + lane*8
        // o1 is re-read by gemm2 -> REGULAR store (keep L2-warm)
        char* O = (char*)out + (size_t)n*512 + lane*8;
        uint2 pk;
        pk.x = (u32)f2bf(a0) | ((u32)f2bf(a1) << 16);
        pk.y = (u32)f2bf(a2) | ((u32)f2bf(a3) << 16);
        *(uint2*)O = pk;
    }
}

// ---------- launch ----------
extern "C" void kernel_launch(void* const* d_in, const int* in_sizes, int n_in,
                              void* d_out, int out_size, void* d_ws, size_t ws_size,
                              hipStream_t stream){
    const float* x  = (const float*)d_in[0];
    const int*   ei = (const int*)  d_in[1];
    const float* ea = (const float*)d_in[2];
    const float* W1 = (const float*)d_in[3];
    const float* b1 = (const float*)d_in[4];
    const float* W2 = (const float*)d_in[5];
    const float* b2 = (const float*)d_in[6];

    char* p = (char*)d_ws;
    auto alloc = [&](size_t bytes)->char*{ char* r = p; p += (bytes + 511) & ~(size_t)511; return r; };
    u64*   part     = (u64*)  alloc((size_t)NXCD*NNODES*8);   // 3.2 MB partial histograms
    u32*   rankpack = (u32*)  alloc((size_t)NEDGE*4);
    int*   poff     = (int*)  alloc((size_t)NXCD*NNODES*4);
    float* dinv     = (float*)alloc(NNODES*4);
    int*   cnt      = (int*)  alloc(NNODES*4);
    int*   colstart = (int*)  alloc(NNODES*4);
    int*   colstartF= (int*)  alloc(NNODES*4);
    int*   bsum     = (int*)  alloc(1024);
    u32*   epk      = (u32*)  alloc((size_t)NEDGE*4);
    u16*   Wt1      = (u16*)  alloc(DIM*DIM*2);
    u16*   Wt2      = (u16*)  alloc(DIM*DIM*2);
    u16*   h        = (u16*)  alloc((size_t)M_TOT*DIM*2);   // bf16, batch-interleaved
    u16*   o1       = (u16*)  alloc((size_t)M_TOT*DIM*2);   // bf16, batch-interleaved

    const int NBL_E = (NEDGE  + 255)/256;
    const int NTILE = (M_TOT + 127)/128;    // 782 (128-row tiles)
    const int NBL_G = (NNODES + 3)/4;       // 12500 (4 node-waves per block)

    transposeW<<<128, 256, 0, stream>>>(W1, Wt1, W2, Wt2, part);
    count_k<<<NBL_E, 256, 0, stream>>>(ei, ea, part, rankpack);
    scan1  <<<NBL_N, 256, 0, stream>>>(part, cnt, poff, dinv, colstart, bsum);
    fill_k <<<NBL_E, 256, 0, stream>>>(ei, ea, dinv, colstart, bsum, poff, rankpack, colstartF, epk);

    gemm128<float, true ><<<NTILE, 256, 0, stream>>>(x,  Wt1, h, M_TOT);
    gather6_k<false><<<NBL_G, 256, 0, stream>>>(h,  epk, colstartF, cnt, dinv, b1, o1);
    gemm128<u16,   false><<<NTILE, 256, 0, stream>>>(o1, Wt2, h, M_TOT);
    gather6_k<true ><<<NBL_G, 256, 0, stream>>>(h,  epk, colstartF, cnt, dinv, b2, d_out);
}

// Round 4
// 293.335 us; speedup vs baseline: 1.0169x; 1.0169x over previous
//
#include <hip/hip_runtime.h>

// Problem constants (GNNNet_678604833376): B=2, N=50000, D=128, E=640000
#define NNODES 50000
#define NBATCH 2
#define DIM    128
#define NEDGE  640000
#define M_TOT  (NBATCH*NNODES)   // 100000 rows for the GEMM
#define NXCD   8
#define NBL_N  196               // ceil(NNODES/256)
#define NBL_E  2500              // NEDGE/256 exactly
#define NTILE  391               // ceil(M_TOT/256)

typedef unsigned short u16;
typedef unsigned int   u32;
typedef unsigned long long u64;

typedef __attribute__((ext_vector_type(8))) short bf16x8;   // 8 bf16 = 4 VGPRs
typedef __attribute__((ext_vector_type(4))) float f32x4;

__device__ __forceinline__ float bf2f(u16 u){ return __uint_as_float(((u32)u)<<16); }
__device__ __forceinline__ u16 f2bf(float f){
    u32 x = __float_as_uint(f);
    x += 0x7fffu + ((x>>16)&1u);   // round-to-nearest-even
    return (u16)(x>>16);
}

// ---------- fused: edge histogram (count) + weight transpose ----------
// part[] is pre-zeroed by hipMemsetAsync. Blocks [0,NBL_E) count edges;
// blocks [NBL_E, NBL_E+128) transpose W1/W2 to bf16. Independent work,
// one launch: overlaps the small transpose under the count.
__global__ __launch_bounds__(256) void prep1_k(const int* __restrict__ ei,
                                               const float* __restrict__ ea,
                                               u64* __restrict__ part,
                                               u32* __restrict__ rankpack,
                                               const float* __restrict__ W1, u16* __restrict__ Wt1,
                                               const float* __restrict__ W2, u16* __restrict__ Wt2){
    int bid = blockIdx.x;
    if (bid < NBL_E){
        u32 xcc = __builtin_amdgcn_s_getreg(6164) & 7u;   // HW_REG_XCC_ID
        int e = bid*256 + threadIdx.x;                    // NEDGE = NBL_E*256 exactly
        int c = ei[NEDGE + e];
        u64 inc = (((u64)__float2uint_rn(ea[e] * 16777216.0f)) << 32) | 1ull;
        u64 old = __hip_atomic_fetch_add(&part[(size_t)xcc*NNODES + c], inc,
                                         __ATOMIC_RELAXED, __HIP_MEMORY_SCOPE_WORKGROUP);
        rankpack[e] = ((u32)old & 0xffffu) | (xcc << 16);
    } else {
        int i = (bid - NBL_E)*256 + threadIdx.x;          // 0..32767
        const float* W = (i < 16384) ? W1 : W2;
        u16* Wt       = (i < 16384) ? Wt1 : Wt2;
        int ii = i & 16383;
        int k = ii >> 7, n = ii & 127;
        Wt[n*DIM + k] = f2bf(W[ii]);
    }
}

// ---------- fused reduce + block-scan ----------
__global__ __launch_bounds__(256) void scan1(const u64* __restrict__ part,
                                             int* __restrict__ cnt,
                                             int* __restrict__ poff,
                                             float* __restrict__ dinv,
                                             int* colstart, int* bsum){
    __shared__ int s[256];
    int tid = threadIdx.x;
    int n = blockIdx.x*256 + tid;
    int v = 0;
    if (n < NNODES){
        int run = 0; u64 fsum = 0;
        #pragma unroll
        for (int p = 0; p < NXCD; ++p){
            u64 pv = part[(size_t)p*NNODES + n];
            poff[p*NNODES + n] = run;
            run  += (int)(pv & 0xffffffffu);
            fsum += (pv >> 32);
        }
        cnt[n] = run;
        v = run;
        float deg = 1.0f + (float)fsum * (1.0f/16777216.0f);   // deg >= 1
        dinv[n] = rsqrtf(deg);
    }
    s[tid] = v; __syncthreads();
    #pragma unroll
    for (int off = 1; off < 256; off <<= 1){
        int t = (tid >= off) ? s[tid-off] : 0;
        __syncthreads();
        s[tid] += t;
        __syncthreads();
    }
    if (n < NNODES) colstart[n] = s[tid] - v;     // exclusive within block
    if (tid == 255) bsum[blockIdx.x] = s[255];
}

// ---------- GEMM body (round-0 structure: 256-row tiles, scalar epilogue) ----------
__device__ __forceinline__ bf16x8 load_frag(const float* A, size_t off){
    const float4* ap = (const float4*)(A + off);
    float4 lo = ap[0], hi = ap[1];
    bf16x8 r;
    r[0] = (short)f2bf(lo.x); r[1] = (short)f2bf(lo.y);
    r[2] = (short)f2bf(lo.z); r[3] = (short)f2bf(lo.w);
    r[4] = (short)f2bf(hi.x); r[5] = (short)f2bf(hi.y);
    r[6] = (short)f2bf(hi.z); r[7] = (short)f2bf(hi.w);
    return r;
}
__device__ __forceinline__ bf16x8 load_frag(const u16* A, size_t off){
    return *(const bf16x8*)(A + off);
}

template <typename AT, bool PERM>
__device__ __forceinline__ void gemm_body(const AT* __restrict__ A,
                                          const u16* __restrict__ Wt,
                                          u16* __restrict__ H, int M,
                                          int tileIdx, u16 (*Wl)[136]){
    int tid = threadIdx.x;
    {
        const uint4* src = (const uint4*)Wt;   // 2048 x 16B
        #pragma unroll
        for (int j = 0; j < 8; ++j){
            int g = tid + j*256;
            int n = g >> 4;
            int k = (g & 15) * 8;
            *(uint4*)&Wl[n][k] = src[g];
        }
    }
    __syncthreads();

    int wave = tid >> 6, lane = tid & 63;
    int quad = lane >> 4, r = lane & 15;
    int row0 = tileIdx*256 + wave*64;

    f32x4 acc[4][8];
    #pragma unroll
    for (int mt = 0; mt < 4; ++mt)
        #pragma unroll
        for (int nt = 0; nt < 8; ++nt)
            acc[mt][nt] = (f32x4){0.f,0.f,0.f,0.f};

    #pragma unroll
    for (int ks = 0; ks < 4; ++ks){
        bf16x8 af[4];
        #pragma unroll
        for (int mt = 0; mt < 4; ++mt){
            int row = row0 + mt*16 + r;
            if (row < M)
                af[mt] = load_frag(A, (size_t)row*DIM + ks*32 + quad*8);
            else
                af[mt] = (bf16x8){0,0,0,0,0,0,0,0};
        }
        #pragma unroll
        for (int nt = 0; nt < 8; ++nt){
            bf16x8 bfr = *(const bf16x8*)&Wl[nt*16 + r][ks*32 + quad*8];
            #pragma unroll
            for (int mt = 0; mt < 4; ++mt)
                acc[mt][nt] = __builtin_amdgcn_mfma_f32_16x16x32_bf16(af[mt], bfr, acc[mt][nt], 0, 0, 0);
        }
    }

    // C/D layout: col = lane&15 (=r), row = quad*4 + reg
    #pragma unroll
    for (int mt = 0; mt < 4; ++mt){
        #pragma unroll
        for (int reg = 0; reg < 4; ++reg){
            int row = row0 + mt*16 + quad*4 + reg;
            if (row < M){
                size_t hrow;
                if (PERM){
                    int b = (row >= NNODES);
                    int n = row - b*NNODES;
                    hrow = (size_t)(2*n + b);
                } else {
                    hrow = (size_t)row;
                }
                #pragma unroll
                for (int nt = 0; nt < 8; ++nt)
                    H[hrow*DIM + nt*16 + r] = f2bf(acc[mt][nt][reg]);
            }
        }
    }
}

template <typename AT, bool PERM>
__global__ __launch_bounds__(256) void gemm128(const AT* __restrict__ A,
                                               const u16* __restrict__ Wt,
                                               u16* __restrict__ H, int M){
    __shared__ u16 Wl[128][136];
    gemm_body<AT, PERM>(A, Wt, H, M, blockIdx.x, Wl);
}

// ---------- fused: CSR bucket fill + gemm1 ----------
// Blocks [0,NTILE) run gemm1 (x @ W1 -> h, PERM); blocks [NTILE, NTILE+NBL_E)
// run the fill. Independent work (gather1 needs both) -> one launch,
// time = max(gemm1, fill) instead of sum. fill aliases the first 2KB of Wl.
__global__ __launch_bounds__(256) void fillgemm_k(const int* __restrict__ ei,
                                                  const float* __restrict__ ea,
                                                  const float* __restrict__ dinv,
                                                  const int* __restrict__ colstart,
                                                  const int* __restrict__ bsum,
                                                  const int* __restrict__ poff,
                                                  const u32* __restrict__ rankpack,
                                                  int* __restrict__ colstartF,
                                                  u32* __restrict__ epk,
                                                  const float* __restrict__ x,
                                                  const u16* __restrict__ Wt1,
                                                  u16* __restrict__ h){
    __shared__ u16 Wl[128][136];
    if (blockIdx.x < NTILE){
        gemm_body<float, true>(x, Wt1, h, M_TOT, blockIdx.x, Wl);
        return;
    }
    // ---- fill branch ----
    int* s   = (int*)&Wl[0][0];
    int* pre = s + 256;
    int tid = threadIdx.x;
    int v = (tid < NBL_N) ? bsum[tid] : 0;
    s[tid] = v; __syncthreads();
    #pragma unroll
    for (int off = 1; off < 256; off <<= 1){
        int t = (tid >= off) ? s[tid-off] : 0;
        __syncthreads();
        s[tid] += t;
        __syncthreads();
    }
    pre[tid] = s[tid] - v;                        // exclusive prefix of bsum
    __syncthreads();

    int e = (blockIdx.x - NTILE)*256 + tid;       // NEDGE = NBL_E*256 exactly
    int r = ei[e], c = ei[NEDGE + e];
    u32 rp = rankpack[e];
    int base = colstart[c] + pre[c >> 8];         // final colstart for c
    colstartF[c] = base;
    int pos = base + poff[(rp >> 16)*NNODES + c] + (int)(rp & 0xffffu);
    float w = dinv[r] * ea[e] * dinv[c];
    epk[pos] = (u32)r | ((u32)f2bf(w) << 16);
}

// ---------- gather-aggregate: one wave = one node, BOTH batches ----------
// H interleaved: Hi[n][batch][128] bf16 -> one edge = one contiguous 512B
// wave-load. 8 loads in flight (round-3 showed 16-deep regresses: the gather
// is bound by the L2-miss service rate, not latency -> 8-deep saturates it).
template <bool OUT_F32>
__global__ __launch_bounds__(256) void gather6_k(const u16* __restrict__ Hi,
                                                 const u32* __restrict__ epk,
                                                 const int* __restrict__ colstartF,
                                                 const int* __restrict__ cnt,
                                                 const float* __restrict__ dinv,
                                                 const float* __restrict__ bias,
                                                 void* __restrict__ out){
    int wave = threadIdx.x >> 6, lane = threadIdx.x & 63;
    int n = blockIdx.x*4 + wave;
    if (n >= NNODES) return;
    const char* Hb = (const char*)Hi;             // row stride 512 B (both batches)

    float a0, a1, a2, a3;
    {
        uint2 sv = *(const uint2*)(Hb + (size_t)n*512 + lane*8);
        float dn = dinv[n], dn2 = dn*dn;
        a0 = dn2*__uint_as_float(sv.x << 16);
        a1 = dn2*__uint_as_float(sv.x & 0xffff0000u);
        a2 = dn2*__uint_as_float(sv.y << 16);
        a3 = dn2*__uint_as_float(sv.y & 0xffff0000u);
    }

    int s = colstartF[n], c = cnt[n];
    for (int base = 0; base < c; base += 64){
        int m = min(64, c - base);
        u32 em = 0;                               // pad: row 0, weight +0.0f
        if (lane < m) em = epk[s + base + lane];
        for (int j = 0; j < m; j += 8){           // 8 edges per iter, 8 loads in flight
            #pragma unroll
            for (int g = 0; g < 8; ++g){
                u32 me = __shfl(em, j + g);       // max idx 56+7 = 63
                uint2 v = *(const uint2*)(Hb + (size_t)(me & 0xffffu)*512 + lane*8);
                float w = __uint_as_float(me & 0xffff0000u);
                a0 = fmaf(w, __uint_as_float(v.x << 16), a0);
                a1 = fmaf(w, __uint_as_float(v.x & 0xffff0000u), a1);
                a2 = fmaf(w, __uint_as_float(v.y << 16), a2);
                a3 = fmaf(w, __uint_as_float(v.y & 0xffff0000u), a3);
            }
        }
    }

    int sub = lane & 31, b = lane >> 5;
    float4 bb = ((const float4*)bias)[sub];       // cols [4*sub .. 4*sub+4), same both batches
    a0 = fmaxf(a0 + bb.x, 0.f);
    a1 = fmaxf(a1 + bb.y, 0.f);
    a2 = fmaxf(a2 + bb.z, 0.f);
    a3 = fmaxf(a3 + bb.w, 0.f);
    if (OUT_F32){
        // de-interleave: d_out row = b*N + n (fp32)
        float* O = (float*)out + ((size_t)b*NNODES + n)*DIM + sub*4;
        *(float4*)O = make_float4(a0, a1, a2, a3);
    } else {
        // stay interleaved (bf16): row 2n+b == byte offset n*512 + lane*8
        char* O = (char*)out + (size_t)n*512 + lane*8;
        uint2 pk;
        pk.x = (u32)f2bf(a0) | ((u32)f2bf(a1) << 16);
        pk.y = (u32)f2bf(a2) | ((u32)f2bf(a3) << 16);
        *(uint2*)O = pk;
    }
}

// ---------- launch ----------
extern "C" void kernel_launch(void* const* d_in, const int* in_sizes, int n_in,
                              void* d_out, int out_size, void* d_ws, size_t ws_size,
                              hipStream_t stream){
    const float* x  = (const float*)d_in[0];
    const int*   ei = (const int*)  d_in[1];
    const float* ea = (const float*)d_in[2];
    const float* W1 = (const float*)d_in[3];
    const float* b1 = (const float*)d_in[4];
    const float* W2 = (const float*)d_in[5];
    const float* b2 = (const float*)d_in[6];

    char* p = (char*)d_ws;
    auto alloc = [&](size_t bytes)->char*{ char* r = p; p += (bytes + 511) & ~(size_t)511; return r; };
    u64*   part     = (u64*)  alloc((size_t)NXCD*NNODES*8);   // 3.2 MB partial histograms
    u32*   rankpack = (u32*)  alloc((size_t)NEDGE*4);
    int*   poff     = (int*)  alloc((size_t)NXCD*NNODES*4);
    float* dinv     = (float*)alloc(NNODES*4);
    int*   cnt      = (int*)  alloc(NNODES*4);
    int*   colstart = (int*)  alloc(NNODES*4);
    int*   colstartF= (int*)  alloc(NNODES*4);
    int*   bsum     = (int*)  alloc(1024);
    u32*   epk      = (u32*)  alloc((size_t)NEDGE*4);
    u16*   Wt1      = (u16*)  alloc(DIM*DIM*2);
    u16*   Wt2      = (u16*)  alloc(DIM*DIM*2);
    u16*   h        = (u16*)  alloc((size_t)M_TOT*DIM*2);   // bf16, batch-interleaved
    u16*   o1       = (u16*)  alloc((size_t)M_TOT*DIM*2);   // bf16, batch-interleaved

    const int NBL_G = (NNODES + 3)/4;       // 12500 (4 node-waves per block)

    hipMemsetAsync(part, 0, (size_t)NXCD*NNODES*8, stream);
    prep1_k<<<NBL_E + 128, 256, 0, stream>>>(ei, ea, part, rankpack, W1, Wt1, W2, Wt2);
    scan1  <<<NBL_N, 256, 0, stream>>>(part, cnt, poff, dinv, colstart, bsum);
    fillgemm_k<<<NTILE + NBL_E, 256, 0, stream>>>(ei, ea, dinv, colstart, bsum, poff,
                                                  rankpack, colstartF, epk, x, Wt1, h);
    gather6_k<false><<<NBL_G, 256, 0, stream>>>(h,  epk, colstartF, cnt, dinv, b1, o1);
    gemm128<u16, false><<<NTILE, 256, 0, stream>>>(o1, Wt2, h, M_TOT);
    gather6_k<true ><<<NBL_G, 256, 0, stream>>>(h,  epk, colstartF, cnt, dinv, b2, d_out);
}

// Round 5
// 286.998 us; speedup vs baseline: 1.0393x; 1.0221x over previous
//
#include <hip/hip_runtime.h>

// Problem constants (GNNNet_678604833376): B=2, N=50000, D=128, E=640000
#define NNODES 50000
#define NBATCH 2
#define DIM    128
#define NEDGE  640000
#define M_TOT  (NBATCH*NNODES)   // 100000 rows for the GEMM
#define NXCD   8
#define NBL_N  196               // ceil(NNODES/256)

typedef unsigned short u16;
typedef unsigned int   u32;
typedef unsigned long long u64;

typedef __attribute__((ext_vector_type(8))) short bf16x8;   // 8 bf16 = 4 VGPRs
typedef __attribute__((ext_vector_type(4))) float f32x4;

__device__ __forceinline__ float bf2f(u16 u){ return __uint_as_float(((u32)u)<<16); }
__device__ __forceinline__ u16 f2bf(float f){
    u32 x = __float_as_uint(f);
    x += 0x7fffu + ((x>>16)&1u);   // round-to-nearest-even
    return (u16)(x>>16);
}

// ---------- histogram: per-XCD partials, L2-resident workgroup-scope atomics ----------
__global__ __launch_bounds__(256) void count_k(const int* __restrict__ ei,
                                               const float* __restrict__ ea,
                                               u64* __restrict__ part,
                                               u32* __restrict__ rankpack){
    u32 xcc = __builtin_amdgcn_s_getreg(6164) & 7u;   // HW_REG_XCC_ID
    int e = blockIdx.x*256 + threadIdx.x;
    if (e < NEDGE){
        int c = ei[NEDGE + e];
        u64 inc = (((u64)__float2uint_rn(ea[e] * 16777216.0f)) << 32) | 1ull;
        u64 old = __hip_atomic_fetch_add(&part[(size_t)xcc*NNODES + c], inc,
                                         __ATOMIC_RELAXED, __HIP_MEMORY_SCOPE_WORKGROUP);
        rankpack[e] = ((u32)old & 0xffffu) | (xcc << 16);
    }
}

// ---------- fused reduce + block-scan ----------
__global__ __launch_bounds__(256) void scan1(const u64* __restrict__ part,
                                             int* __restrict__ cnt,
                                             int* __restrict__ poff,
                                             float* __restrict__ dinv,
                                             int* colstart, int* bsum){
    __shared__ int s[256];
    int tid = threadIdx.x;
    int n = blockIdx.x*256 + tid;
    int v = 0;
    if (n < NNODES){
        int run = 0; u64 fsum = 0;
        #pragma unroll
        for (int p = 0; p < NXCD; ++p){
            u64 pv = part[(size_t)p*NNODES + n];
            poff[p*NNODES + n] = run;
            run  += (int)(pv & 0xffffffffu);
            fsum += (pv >> 32);
        }
        cnt[n] = run;
        v = run;
        float deg = 1.0f + (float)fsum * (1.0f/16777216.0f);   // deg >= 1
        dinv[n] = rsqrtf(deg);
    }
    s[tid] = v; __syncthreads();
    #pragma unroll
    for (int off = 1; off < 256; off <<= 1){
        int t = (tid >= off) ? s[tid-off] : 0;
        __syncthreads();
        s[tid] += t;
        __syncthreads();
    }
    if (n < NNODES) colstart[n] = s[tid] - v;     // exclusive within block
    if (tid == 255) bsum[blockIdx.x] = s[255];
}

// ---------- CSR bucket fill + inline bsum-scan ----------
// epk[pos] = row | (bf16(norm) << 16)   (row < 50000 fits in 16 bits)
__global__ __launch_bounds__(256) void fill_k(const int* __restrict__ ei,
                                              const float* __restrict__ ea,
                                              const float* __restrict__ dinv,
                                              const int* __restrict__ colstart,
                                              const int* __restrict__ bsum,
                                              const int* __restrict__ poff,
                                              const u32* __restrict__ rankpack,
                                              int* __restrict__ colstartF,
                                              u32* __restrict__ epk){
    __shared__ int s[256];
    __shared__ int pre[256];
    int tid = threadIdx.x;
    int v = (tid < NBL_N) ? bsum[tid] : 0;
    s[tid] = v; __syncthreads();
    #pragma unroll
    for (int off = 1; off < 256; off <<= 1){
        int t = (tid >= off) ? s[tid-off] : 0;
        __syncthreads();
        s[tid] += t;
        __syncthreads();
    }
    pre[tid] = s[tid] - v;                        // exclusive prefix of bsum
    __syncthreads();

    int e = blockIdx.x*256 + tid;
    if (e < NEDGE){
        int r = ei[e], c = ei[NEDGE + e];
        u32 rp = rankpack[e];
        int base = colstart[c] + pre[c >> 8];     // final colstart for c
        colstartF[c] = base;
        int pos = base + poff[(rp >> 16)*NNODES + c] + (int)(rp & 0xffffu);
        float w = dinv[r] * ea[e] * dinv[c];
        epk[pos] = (u32)r | ((u32)f2bf(w) << 16);
    }
}

// transpose both W (fp32) -> Wt (bf16), Wt[n][k] = W[k][n]; also zero part[].
__global__ __launch_bounds__(256) void transposeW(const float* __restrict__ W1, u16* __restrict__ Wt1,
                                                  const float* __restrict__ W2, u16* __restrict__ Wt2,
                                                  u64* __restrict__ part){
    int i = blockIdx.x*256 + threadIdx.x;         // 128 x 256 = 32768 threads
    const float* W = (i < 16384) ? W1 : W2;
    u16* Wt       = (i < 16384) ? Wt1 : Wt2;
    int ii = i & 16383;
    int k = ii >> 7, n = ii & 127;
    Wt[n*DIM + k] = f2bf(W[ii]);
    // zero the 8x50000 u64 histogram: 400000 u64 / 32768 thr = 13 each
    for (int z = i; z < NXCD*NNODES; z += 32768) part[z] = 0;
}

// ---------- GEMM: H(bf16) = A(AT->bf16) @ W[128,128] ----------
// Round-4 diagnosis: old 256-row design ran at VGPR=144 (3 waves/SIMD),
// MfmaUtil 2%, VALUBusy 6%, occupancy ~9% -> latency-starved; scalar 2B
// epilogue showed 1.76x write amplification. New design: 128-row tiles,
// acc[2][8]=64 VGPR, __launch_bounds__(256,4) -> 4 blocks/CU (16 waves/CU);
// LDS-staged epilogue (reuses W buffer) -> coalesced 16B row stores.
__device__ __forceinline__ bf16x8 load_frag(const float* A, size_t off){
    // x input: read exactly once -> nt keeps L2 for h
    const f32x4* ap = (const f32x4*)(A + off);
    f32x4 lo = __builtin_nontemporal_load(ap);
    f32x4 hi = __builtin_nontemporal_load(ap + 1);
    bf16x8 r;
    r[0] = (short)f2bf(lo.x); r[1] = (short)f2bf(lo.y);
    r[2] = (short)f2bf(lo.z); r[3] = (short)f2bf(lo.w);
    r[4] = (short)f2bf(hi.x); r[5] = (short)f2bf(hi.y);
    r[6] = (short)f2bf(hi.z); r[7] = (short)f2bf(hi.w);
    return r;
}
__device__ __forceinline__ bf16x8 load_frag(const u16* A, size_t off){
    // o1 input: just written by gather1 -> want the L2 hit, regular load
    return *(const bf16x8*)(A + off);
}

template <typename AT, bool PERM>
__global__ __launch_bounds__(256, 4) void gemm128(const AT* __restrict__ A,
                                                  const u16* __restrict__ Wt,
                                                  u16* __restrict__ H, int M){
    __shared__ u16 Wl[128][136];   // 34.8KB; W tile, reused as C-stage
    int tid = threadIdx.x;
    {
        const uint4* src = (const uint4*)Wt;   // 2048 x 16B
        #pragma unroll
        for (int j = 0; j < 8; ++j){
            int g = tid + j*256;
            *(uint4*)&Wl[g >> 4][(g & 15)*8] = src[g];
        }
    }
    __syncthreads();

    int wave = tid >> 6, lane = tid & 63;
    int quad = lane >> 4, r = lane & 15;
    int row0 = blockIdx.x*128;
    int rbase = row0 + wave*32;            // each wave: 32 rows (mt=0,1)

    f32x4 acc[2][8];
    #pragma unroll
    for (int mt = 0; mt < 2; ++mt)
        #pragma unroll
        for (int nt = 0; nt < 8; ++nt)
            acc[mt][nt] = (f32x4){0.f,0.f,0.f,0.f};

    #pragma unroll
    for (int ks = 0; ks < 4; ++ks){
        bf16x8 af[2];
        #pragma unroll
        for (int mt = 0; mt < 2; ++mt){
            int row = rbase + mt*16 + r;
            if (row < M)
                af[mt] = load_frag(A, (size_t)row*DIM + ks*32 + quad*8);
            else
                af[mt] = (bf16x8){0,0,0,0,0,0,0,0};
        }
        #pragma unroll
        for (int nt = 0; nt < 8; ++nt){
            bf16x8 bfr = *(const bf16x8*)&Wl[nt*16 + r][ks*32 + quad*8];
            #pragma unroll
            for (int mt = 0; mt < 2; ++mt)
                acc[mt][nt] = __builtin_amdgcn_mfma_f32_16x16x32_bf16(af[mt], bfr, acc[mt][nt], 0, 0, 0);
        }
    }

    // all waves done reading Wl -> reuse as C-stage (128 rows x 128 u16)
    __syncthreads();
    // C/D layout: col = lane&15 (=r), row = quad*4 + reg
    #pragma unroll
    for (int mt = 0; mt < 2; ++mt)
        #pragma unroll
        for (int nt = 0; nt < 8; ++nt)
            #pragma unroll
            for (int reg = 0; reg < 4; ++reg)
                Wl[wave*32 + mt*16 + quad*4 + reg][nt*16 + r] = f2bf(acc[mt][nt][reg]);
    __syncthreads();

    // coalesced 16B REGULAR stores (h is re-read by gather: keep L2-warm)
    #pragma unroll
    for (int j = 0; j < 8; ++j){
        int g = tid + j*256;                  // 2048 chunks = 128 rows x 16 chunks
        int rl = g >> 4, ch = g & 15;
        int row = row0 + rl;
        if (row < M){
            size_t hrow;
            if (PERM){
                int b = (row >= NNODES);
                hrow = (size_t)(2*(row - b*NNODES) + b);
            } else {
                hrow = (size_t)row;
            }
            *(uint4*)((char*)H + hrow*256 + ch*16) = *(const uint4*)&Wl[rl][ch*8];
        }
    }
}

// ---------- gather-aggregate: one wave = one node, BOTH batches ----------
// H interleaved: Hi[n][batch][128] bf16 -> one edge = one contiguous 512B
// wave-load. 8 loads in flight (16-deep measured worse in round 3: bound by
// L2-miss service rate of the XCD-replicated 25.6MB H, not latency).
template <bool OUT_F32>
__global__ __launch_bounds__(256) void gather6_k(const u16* __restrict__ Hi,
                                                 const u32* __restrict__ epk,
                                                 const int* __restrict__ colstartF,
                                                 const int* __restrict__ cnt,
                                                 const float* __restrict__ dinv,
                                                 const float* __restrict__ bias,
                                                 void* __restrict__ out){
    int wave = threadIdx.x >> 6, lane = threadIdx.x & 63;
    int n = blockIdx.x*4 + wave;
    if (n >= NNODES) return;
    const char* Hb = (const char*)Hi;             // row stride 512 B (both batches)

    float a0, a1, a2, a3;
    {
        uint2 sv = *(const uint2*)(Hb + (size_t)n*512 + lane*8);
        float dn = dinv[n], dn2 = dn*dn;
        a0 = dn2*__uint_as_float(sv.x << 16);
        a1 = dn2*__uint_as_float(sv.x & 0xffff0000u);
        a2 = dn2*__uint_as_float(sv.y << 16);
        a3 = dn2*__uint_as_float(sv.y & 0xffff0000u);
    }

    int s = colstartF[n], c = cnt[n];
    for (int base = 0; base < c; base += 64){
        int m = min(64, c - base);
        u32 em = 0;                               // pad: row 0, weight +0.0f
        if (lane < m) em = epk[s + base + lane];
        for (int j = 0; j < m; j += 8){           // 8 edges per iter, 8 loads in flight
            #pragma unroll
            for (int g = 0; g < 8; ++g){
                u32 me = __shfl(em, j + g);       // max idx 56+7 = 63
                uint2 v = *(const uint2*)(Hb + (size_t)(me & 0xffffu)*512 + lane*8);
                float w = __uint_as_float(me & 0xffff0000u);
                a0 = fmaf(w, __uint_as_float(v.x << 16), a0);
                a1 = fmaf(w, __uint_as_float(v.x & 0xffff0000u), a1);
                a2 = fmaf(w, __uint_as_float(v.y << 16), a2);
                a3 = fmaf(w, __uint_as_float(v.y & 0xffff0000u), a3);
            }
        }
    }

    int sub = lane & 31, b = lane >> 5;
    float4 bb = ((const float4*)bias)[sub];       // cols [4*sub .. 4*sub+4), same both batches
    a0 = fmaxf(a0 + bb.x, 0.f);
    a1 = fmaxf(a1 + bb.y, 0.f);
    a2 = fmaxf(a2 + bb.z, 0.f);
    a3 = fmaxf(a3 + bb.w, 0.f);
    if (OUT_F32){
        // de-interleave: d_out row = b*N + n (fp32)
        float* O = (float*)out + ((size_t)b*NNODES + n)*DIM + sub*4;
        *(float4*)O = make_float4(a0, a1, a2, a3);
    } else {
        // stay interleaved (bf16): row 2n+b == byte offset n*512 + lane*8
        char* O = (char*)out + (size_t)n*512 + lane*8;
        uint2 pk;
        pk.x = (u32)f2bf(a0) | ((u32)f2bf(a1) << 16);
        pk.y = (u32)f2bf(a2) | ((u32)f2bf(a3) << 16);
        *(uint2*)O = pk;
    }
}

// ---------- launch ----------
extern "C" void kernel_launch(void* const* d_in, const int* in_sizes, int n_in,
                              void* d_out, int out_size, void* d_ws, size_t ws_size,
                              hipStream_t stream){
    const float* x  = (const float*)d_in[0];
    const int*   ei = (const int*)  d_in[1];
    const float* ea = (const float*)d_in[2];
    const float* W1 = (const float*)d_in[3];
    const float* b1 = (const float*)d_in[4];
    const float* W2 = (const float*)d_in[5];
    const float* b2 = (const float*)d_in[6];

    char* p = (char*)d_ws;
    auto alloc = [&](size_t bytes)->char*{ char* r = p; p += (bytes + 511) & ~(size_t)511; return r; };
    u64*   part     = (u64*)  alloc((size_t)NXCD*NNODES*8);   // 3.2 MB partial histograms
    u32*   rankpack = (u32*)  alloc((size_t)NEDGE*4);
    int*   poff     = (int*)  alloc((size_t)NXCD*NNODES*4);
    float* dinv     = (float*)alloc(NNODES*4);
    int*   cnt      = (int*)  alloc(NNODES*4);
    int*   colstart = (int*)  alloc(NNODES*4);
    int*   colstartF= (int*)  alloc(NNODES*4);
    int*   bsum     = (int*)  alloc(1024);
    u32*   epk      = (u32*)  alloc((size_t)NEDGE*4);
    u16*   Wt1      = (u16*)  alloc(DIM*DIM*2);
    u16*   Wt2      = (u16*)  alloc(DIM*DIM*2);
    u16*   h        = (u16*)  alloc((size_t)M_TOT*DIM*2);   // bf16, batch-interleaved
    u16*   o1       = (u16*)  alloc((size_t)M_TOT*DIM*2);   // bf16, batch-interleaved

    const int NBL_E = (NEDGE  + 255)/256;
    const int NTILE = (M_TOT + 127)/128;    // 782 (128-row tiles)
    const int NBL_G = (NNODES + 3)/4;       // 12500 (4 node-waves per block)

    transposeW<<<128, 256, 0, stream>>>(W1, Wt1, W2, Wt2, part);
    count_k<<<NBL_E, 256, 0, stream>>>(ei, ea, part, rankpack);
    scan1  <<<NBL_N, 256, 0, stream>>>(part, cnt, poff, dinv, colstart, bsum);
    fill_k <<<NBL_E, 256, 0, stream>>>(ei, ea, dinv, colstart, bsum, poff, rankpack, colstartF, epk);

    gemm128<float, true ><<<NTILE, 256, 0, stream>>>(x,  Wt1, h, M_TOT);
    gather6_k<false><<<NBL_G, 256, 0, stream>>>(h,  epk, colstartF, cnt, dinv, b1, o1);
    gemm128<u16,   false><<<NTILE, 256, 0, stream>>>(o1, Wt2, h, M_TOT);
    gather6_k<true ><<<NBL_G, 256, 0, stream>>>(h,  epk, colstartF, cnt, dinv, b2, d_out);
}

// Round 6
// 277.751 us; speedup vs baseline: 1.0739x; 1.0333x over previous
//
#include <hip/hip_runtime.h>

// Problem constants (GNNNet_678604833376): B=2, N=50000, D=128, E=640000
#define NNODES 50000
#define NBATCH 2
#define DIM    128
#define NEDGE  640000
#define M_TOT  (NBATCH*NNODES)   // 100000 rows for the GEMM
#define NXCD   8
#define NBL_N  196               // ceil(NNODES/256)
#define NBL_GB 6250              // NNODES/8 nodes per block per batch pass

typedef unsigned short u16;
typedef unsigned int   u32;
typedef unsigned long long u64;

typedef __attribute__((ext_vector_type(8))) short bf16x8;   // 8 bf16 = 4 VGPRs
typedef __attribute__((ext_vector_type(4))) float f32x4;

__device__ __forceinline__ float bf2f(u16 u){ return __uint_as_float(((u32)u)<<16); }
__device__ __forceinline__ u16 f2bf(float f){
    u32 x = __float_as_uint(f);
    x += 0x7fffu + ((x>>16)&1u);   // round-to-nearest-even
    return (u16)(x>>16);
}

// ---------- histogram: per-XCD partials, L2-resident workgroup-scope atomics ----------
__global__ __launch_bounds__(256) void count_k(const int* __restrict__ ei,
                                               const float* __restrict__ ea,
                                               u64* __restrict__ part,
                                               u32* __restrict__ rankpack){
    u32 xcc = __builtin_amdgcn_s_getreg(6164) & 7u;   // HW_REG_XCC_ID
    int e = blockIdx.x*256 + threadIdx.x;
    if (e < NEDGE){
        int c = ei[NEDGE + e];
        u64 inc = (((u64)__float2uint_rn(ea[e] * 16777216.0f)) << 32) | 1ull;
        u64 old = __hip_atomic_fetch_add(&part[(size_t)xcc*NNODES + c], inc,
                                         __ATOMIC_RELAXED, __HIP_MEMORY_SCOPE_WORKGROUP);
        rankpack[e] = ((u32)old & 0xffffu) | (xcc << 16);
    }
}

// ---------- fused reduce + block-scan ----------
__global__ __launch_bounds__(256) void scan1(const u64* __restrict__ part,
                                             int* __restrict__ cnt,
                                             int* __restrict__ poff,
                                             float* __restrict__ dinv,
                                             int* colstart, int* bsum){
    __shared__ int s[256];
    int tid = threadIdx.x;
    int n = blockIdx.x*256 + tid;
    int v = 0;
    if (n < NNODES){
        int run = 0; u64 fsum = 0;
        #pragma unroll
        for (int p = 0; p < NXCD; ++p){
            u64 pv = part[(size_t)p*NNODES + n];
            poff[p*NNODES + n] = run;
            run  += (int)(pv & 0xffffffffu);
            fsum += (pv >> 32);
        }
        cnt[n] = run;
        v = run;
        float deg = 1.0f + (float)fsum * (1.0f/16777216.0f);   // deg >= 1
        dinv[n] = rsqrtf(deg);
    }
    s[tid] = v; __syncthreads();
    #pragma unroll
    for (int off = 1; off < 256; off <<= 1){
        int t = (tid >= off) ? s[tid-off] : 0;
        __syncthreads();
        s[tid] += t;
        __syncthreads();
    }
    if (n < NNODES) colstart[n] = s[tid] - v;     // exclusive within block
    if (tid == 255) bsum[blockIdx.x] = s[255];
}

// ---------- CSR bucket fill + inline bsum-scan ----------
// epk[pos] = row | (bf16(norm) << 16)   (row < 50000 fits in 16 bits)
__global__ __launch_bounds__(256) void fill_k(const int* __restrict__ ei,
                                              const float* __restrict__ ea,
                                              const float* __restrict__ dinv,
                                              const int* __restrict__ colstart,
                                              const int* __restrict__ bsum,
                                              const int* __restrict__ poff,
                                              const u32* __restrict__ rankpack,
                                              int* __restrict__ colstartF,
                                              u32* __restrict__ epk){
    __shared__ int s[256];
    __shared__ int pre[256];
    int tid = threadIdx.x;
    int v = (tid < NBL_N) ? bsum[tid] : 0;
    s[tid] = v; __syncthreads();
    #pragma unroll
    for (int off = 1; off < 256; off <<= 1){
        int t = (tid >= off) ? s[tid-off] : 0;
        __syncthreads();
        s[tid] += t;
        __syncthreads();
    }
    pre[tid] = s[tid] - v;                        // exclusive prefix of bsum
    __syncthreads();

    int e = blockIdx.x*256 + tid;
    if (e < NEDGE){
        int r = ei[e], c = ei[NEDGE + e];
        u32 rp = rankpack[e];
        int base = colstart[c] + pre[c >> 8];     // final colstart for c
        colstartF[c] = base;
        int pos = base + poff[(rp >> 16)*NNODES + c] + (int)(rp & 0xffffu);
        float w = dinv[r] * ea[e] * dinv[c];
        epk[pos] = (u32)r | ((u32)f2bf(w) << 16);
    }
}

// transpose both W (fp32) -> Wt (bf16), Wt[n][k] = W[k][n]; also zero part[].
__global__ __launch_bounds__(256) void transposeW(const float* __restrict__ W1, u16* __restrict__ Wt1,
                                                  const float* __restrict__ W2, u16* __restrict__ Wt2,
                                                  u64* __restrict__ part){
    int i = blockIdx.x*256 + threadIdx.x;         // 128 x 256 = 32768 threads
    const float* W = (i < 16384) ? W1 : W2;
    u16* Wt       = (i < 16384) ? Wt1 : Wt2;
    int ii = i & 16383;
    int k = ii >> 7, n = ii & 127;
    Wt[n*DIM + k] = f2bf(W[ii]);
    // zero the 8x50000 u64 histogram: 400000 u64 / 32768 thr = 13 each
    for (int z = i; z < NXCD*NNODES; z += 32768) part[z] = 0;
}

// ---------- GEMM: H(bf16) = A(AT->bf16) @ W[128,128], identity row layout ----------
// 128-row tiles, acc[2][8]=64 VGPR, launch_bounds(256,4); LDS-staged epilogue
// (reuses W buffer) -> coalesced 16B row stores. No PERM: h rows are b*N+n.
__device__ __forceinline__ bf16x8 load_frag(const float* A, size_t off){
    // x input: read exactly once -> nt keeps L2 for h
    const f32x4* ap = (const f32x4*)(A + off);
    f32x4 lo = __builtin_nontemporal_load(ap);
    f32x4 hi = __builtin_nontemporal_load(ap + 1);
    bf16x8 r;
    r[0] = (short)f2bf(lo.x); r[1] = (short)f2bf(lo.y);
    r[2] = (short)f2bf(lo.z); r[3] = (short)f2bf(lo.w);
    r[4] = (short)f2bf(hi.x); r[5] = (short)f2bf(hi.y);
    r[6] = (short)f2bf(hi.z); r[7] = (short)f2bf(hi.w);
    return r;
}
__device__ __forceinline__ bf16x8 load_frag(const u16* A, size_t off){
    // o1 input: just written by gather1 -> want the L2 hit, regular load
    return *(const bf16x8*)(A + off);
}

template <typename AT>
__global__ __launch_bounds__(256, 4) void gemm128(const AT* __restrict__ A,
                                                  const u16* __restrict__ Wt,
                                                  u16* __restrict__ H, int M){
    __shared__ u16 Wl[128][136];   // 34.8KB; W tile, reused as C-stage
    int tid = threadIdx.x;
    {
        const uint4* src = (const uint4*)Wt;   // 2048 x 16B
        #pragma unroll
        for (int j = 0; j < 8; ++j){
            int g = tid + j*256;
            *(uint4*)&Wl[g >> 4][(g & 15)*8] = src[g];
        }
    }
    __syncthreads();

    int wave = tid >> 6, lane = tid & 63;
    int quad = lane >> 4, r = lane & 15;
    int row0 = blockIdx.x*128;
    int rbase = row0 + wave*32;            // each wave: 32 rows (mt=0,1)

    f32x4 acc[2][8];
    #pragma unroll
    for (int mt = 0; mt < 2; ++mt)
        #pragma unroll
        for (int nt = 0; nt < 8; ++nt)
            acc[mt][nt] = (f32x4){0.f,0.f,0.f,0.f};

    #pragma unroll
    for (int ks = 0; ks < 4; ++ks){
        bf16x8 af[2];
        #pragma unroll
        for (int mt = 0; mt < 2; ++mt){
            int row = rbase + mt*16 + r;
            if (row < M)
                af[mt] = load_frag(A, (size_t)row*DIM + ks*32 + quad*8);
            else
                af[mt] = (bf16x8){0,0,0,0,0,0,0,0};
        }
        #pragma unroll
        for (int nt = 0; nt < 8; ++nt){
            bf16x8 bfr = *(const bf16x8*)&Wl[nt*16 + r][ks*32 + quad*8];
            #pragma unroll
            for (int mt = 0; mt < 2; ++mt)
                acc[mt][nt] = __builtin_amdgcn_mfma_f32_16x16x32_bf16(af[mt], bfr, acc[mt][nt], 0, 0, 0);
        }
    }

    // all waves done reading Wl -> reuse as C-stage (128 rows x 128 u16)
    __syncthreads();
    // C/D layout: col = lane&15 (=r), row = quad*4 + reg
    #pragma unroll
    for (int mt = 0; mt < 2; ++mt)
        #pragma unroll
        for (int nt = 0; nt < 8; ++nt)
            #pragma unroll
            for (int reg = 0; reg < 4; ++reg)
                Wl[wave*32 + mt*16 + quad*4 + reg][nt*16 + r] = f2bf(acc[mt][nt][reg]);
    __syncthreads();

    // coalesced 16B REGULAR stores (h is re-read by gather: keep L2-warm)
    #pragma unroll
    for (int j = 0; j < 8; ++j){
        int g = tid + j*256;                  // 2048 chunks = 128 rows x 16 chunks
        int rl = g >> 4, ch = g & 15;
        int row = row0 + rl;
        if (row < M)
            *(uint4*)((char*)H + (size_t)row*256 + ch*16) = *(const uint4*)&Wl[rl][ch*8];
    }
}

// ---------- gather-aggregate: one HALF-wave = one node, batch-split passes ----------
// H identity layout [b*N+n][128] bf16: one edge = 256B contiguous, 32 lanes x 8B.
// Blocks [0,6250) process batch 0, [6250,12500) batch 1: in-order dispatch keeps
// the two 12.8MB working sets temporally separated -> higher per-XCD L2 hit rate
// than the 25.6MB interleaved working set. Per-node edge order preserved exactly.
// 8 loads in flight per lane (round-0's proven depth; 16 measured worse).
template <bool OUT_F32>
__global__ __launch_bounds__(256) void gather8_k(const u16* __restrict__ H,
                                                 const u32* __restrict__ epk,
                                                 const int* __restrict__ colstartF,
                                                 const int* __restrict__ cnt,
                                                 const float* __restrict__ dinv,
                                                 const float* __restrict__ bias,
                                                 void* __restrict__ out){
    int wave = threadIdx.x >> 6, lane = threadIdx.x & 63;
    int sub = lane & 31, half = lane >> 5;
    int bid = blockIdx.x;
    int b   = (bid >= NBL_GB);
    int n   = (bid - b*NBL_GB)*8 + wave*2 + half;   // 50000 = 6250*8 exactly
    const char* Hb = (const char*)(H + (size_t)b*NNODES*DIM);   // row stride 256 B

    float a0, a1, a2, a3;
    {
        uint2 sv = *(const uint2*)(Hb + (size_t)n*256 + sub*8);
        float dn = dinv[n], dn2 = dn*dn;
        a0 = dn2*__uint_as_float(sv.x << 16);
        a1 = dn2*__uint_as_float(sv.x & 0xffff0000u);
        a2 = dn2*__uint_as_float(sv.y << 16);
        a3 = dn2*__uint_as_float(sv.y & 0xffff0000u);
    }

    int s = colstartF[n], c = cnt[n];
    for (int base = 0; base < c; base += 32){
        int m = min(32, c - base);
        u32 em = 0;                               // pad: row 0, weight +0.0f
        if (sub < m) em = epk[s + base + sub];
        for (int j = 0; j < m; j += 8){           // 8 edges per iter, 8 loads in flight
            #pragma unroll
            for (int g = 0; g < 8; ++g){
                u32 me = __shfl(em, half*32 + j + g);   // own half's em lanes
                uint2 v = *(const uint2*)(Hb + (size_t)(me & 0xffffu)*256 + sub*8);
                float w = __uint_as_float(me & 0xffff0000u);
                a0 = fmaf(w, __uint_as_float(v.x << 16), a0);
                a1 = fmaf(w, __uint_as_float(v.x & 0xffff0000u), a1);
                a2 = fmaf(w, __uint_as_float(v.y << 16), a2);
                a3 = fmaf(w, __uint_as_float(v.y & 0xffff0000u), a3);
            }
        }
    }

    float4 bb = ((const float4*)bias)[sub];       // cols [4*sub .. 4*sub+4)
    a0 = fmaxf(a0 + bb.x, 0.f);
    a1 = fmaxf(a1 + bb.y, 0.f);
    a2 = fmaxf(a2 + bb.z, 0.f);
    a3 = fmaxf(a3 + bb.w, 0.f);
    if (OUT_F32){
        // d_out row = b*N + n (fp32), natural layout
        float* O = (float*)out + ((size_t)b*NNODES + n)*DIM + sub*4;
        *(float4*)O = make_float4(a0, a1, a2, a3);
    } else {
        // o1 row = b*N + n (bf16 identity)
        char* O = (char*)out + ((size_t)b*NNODES + n)*256 + sub*8;
        uint2 pk;
        pk.x = (u32)f2bf(a0) | ((u32)f2bf(a1) << 16);
        pk.y = (u32)f2bf(a2) | ((u32)f2bf(a3) << 16);
        *(uint2*)O = pk;
    }
}

// ---------- launch ----------
extern "C" void kernel_launch(void* const* d_in, const int* in_sizes, int n_in,
                              void* d_out, int out_size, void* d_ws, size_t ws_size,
                              hipStream_t stream){
    const float* x  = (const float*)d_in[0];
    const int*   ei = (const int*)  d_in[1];
    const float* ea = (const float*)d_in[2];
    const float* W1 = (const float*)d_in[3];
    const float* b1 = (const float*)d_in[4];
    const float* W2 = (const float*)d_in[5];
    const float* b2 = (const float*)d_in[6];

    char* p = (char*)d_ws;
    auto alloc = [&](size_t bytes)->char*{ char* r = p; p += (bytes + 511) & ~(size_t)511; return r; };
    u64*   part     = (u64*)  alloc((size_t)NXCD*NNODES*8);   // 3.2 MB partial histograms
    u32*   rankpack = (u32*)  alloc((size_t)NEDGE*4);
    int*   poff     = (int*)  alloc((size_t)NXCD*NNODES*4);
    float* dinv     = (float*)alloc(NNODES*4);
    int*   cnt      = (int*)  alloc(NNODES*4);
    int*   colstart = (int*)  alloc(NNODES*4);
    int*   colstartF= (int*)  alloc(NNODES*4);
    int*   bsum     = (int*)  alloc(1024);
    u32*   epk      = (u32*)  alloc((size_t)NEDGE*4);
    u16*   Wt1      = (u16*)  alloc(DIM*DIM*2);
    u16*   Wt2      = (u16*)  alloc(DIM*DIM*2);
    u16*   h        = (u16*)  alloc((size_t)M_TOT*DIM*2);   // bf16, identity layout
    u16*   o1       = (u16*)  alloc((size_t)M_TOT*DIM*2);   // bf16, identity layout

    const int NBL_E = (NEDGE  + 255)/256;
    const int NTILE = (M_TOT + 127)/128;    // 782 (128-row tiles)
    const int NBL_G = 2*NBL_GB;             // 12500: batch 0 then batch 1

    transposeW<<<128, 256, 0, stream>>>(W1, Wt1, W2, Wt2, part);
    count_k<<<NBL_E, 256, 0, stream>>>(ei, ea, part, rankpack);
    scan1  <<<NBL_N, 256, 0, stream>>>(part, cnt, poff, dinv, colstart, bsum);
    fill_k <<<NBL_E, 256, 0, stream>>>(ei, ea, dinv, colstart, bsum, poff, rankpack, colstartF, epk);

    gemm128<float><<<NTILE, 256, 0, stream>>>(x,  Wt1, h, M_TOT);
    gather8_k<false><<<NBL_G, 256, 0, stream>>>(h,  epk, colstartF, cnt, dinv, b1, o1);
    gemm128<u16  ><<<NTILE, 256, 0, stream>>>(o1, Wt2, h, M_TOT);
    gather8_k<true ><<<NBL_G, 256, 0, stream>>>(h,  epk, colstartF, cnt, dinv, b2, d_out);
}